// Round 1
// baseline (1042.636 us; speedup 1.0000x reference)
//
#include <hip/hip_runtime.h>
#include <math.h>

// Fixed problem shape
#define BB 8
#define SS 1024
#define DD 512
#define FF 2048
#define NH 8
#define DH 64
#define MM (BB * SS)   // 8192 rows

// ---------------------------------------------------------------------------
// LayerNorm: one wave per row of 512 floats. block=256 (4 waves), grid=2048.
// ---------------------------------------------------------------------------
__global__ __launch_bounds__(256) void ln_kernel(const float* __restrict__ x,
                                                 const float* __restrict__ g,
                                                 const float* __restrict__ bta,
                                                 float* __restrict__ out) {
  int wave = threadIdx.x >> 6;
  int lane = threadIdx.x & 63;
  int row = blockIdx.x * 4 + wave;
  const float* xr = x + (size_t)row * DD;
  int base = lane * 8;
  float4 v0 = *(const float4*)(xr + base);
  float4 v1 = *(const float4*)(xr + base + 4);
  float s  = v0.x + v0.y + v0.z + v0.w + v1.x + v1.y + v1.z + v1.w;
  float sq = v0.x*v0.x + v0.y*v0.y + v0.z*v0.z + v0.w*v0.w
           + v1.x*v1.x + v1.y*v1.y + v1.z*v1.z + v1.w*v1.w;
  for (int m = 32; m; m >>= 1) {
    s  += __shfl_xor(s, m);
    sq += __shfl_xor(sq, m);
  }
  float mu  = s * (1.0f / DD);
  float var = sq * (1.0f / DD) - mu * mu;
  float rs  = rsqrtf(var + 1e-5f);
  float* orow = out + (size_t)row * DD;
  float go[8], bo[8], xv[8];
  *(float4*)(xv)     = v0;  *(float4*)(xv + 4) = v1;
  *(float4*)(go)     = *(const float4*)(g + base);
  *(float4*)(go + 4) = *(const float4*)(g + base + 4);
  *(float4*)(bo)     = *(const float4*)(bta + base);
  *(float4*)(bo + 4) = *(const float4*)(bta + base + 4);
  float ov[8];
#pragma unroll
  for (int i = 0; i < 8; i++) ov[i] = (xv[i] - mu) * rs * go[i] + bo[i];
  *(float4*)(orow + base)     = *(float4*)(ov);
  *(float4*)(orow + base + 4) = *(float4*)(ov + 4);
}

// ---------------------------------------------------------------------------
// Generic fp32 GEMM: C[M,N] = act(A[M,K] @ W[K,N] + bias) + res
// BM=BN=64, BK=16, block=256 threads, 4x4 per thread.
// act: 0 = none, 1 = gelu(exact, erf-based)
// ---------------------------------------------------------------------------
__global__ __launch_bounds__(256) void gemm_kernel(
    const float* __restrict__ A, const float* __restrict__ W,
    const float* __restrict__ bias, const float* __restrict__ res,
    float* __restrict__ C, int M, int N, int K, int act) {
  __shared__ float As[16][68];  // transposed A tile: As[k][m]
  __shared__ float Bs[16][68];  // Bs[k][n]
  int tx = threadIdx.x & 15, ty = threadIdx.x >> 4;
  int n0 = blockIdx.x * 64, m0 = blockIdx.y * 64;
  float acc[4][4] = {};
  int am = threadIdx.x >> 2, ak = (threadIdx.x & 3) << 2;
  int bk = threadIdx.x >> 4, bn = (threadIdx.x & 15) << 2;
  for (int k0 = 0; k0 < K; k0 += 16) {
    float4 av = *(const float4*)(A + (size_t)(m0 + am) * K + k0 + ak);
    As[ak + 0][am] = av.x; As[ak + 1][am] = av.y;
    As[ak + 2][am] = av.z; As[ak + 3][am] = av.w;
    *(float4*)(&Bs[bk][bn]) =
        *(const float4*)(W + (size_t)(k0 + bk) * N + n0 + bn);
    __syncthreads();
#pragma unroll
    for (int k = 0; k < 16; k++) {
      float a[4], b[4];
      *(float4*)a = *(const float4*)(&As[k][ty << 2]);
      *(float4*)b = *(const float4*)(&Bs[k][tx << 2]);
#pragma unroll
      for (int i = 0; i < 4; i++)
#pragma unroll
        for (int j = 0; j < 4; j++) acc[i][j] = fmaf(a[i], b[j], acc[i][j]);
    }
    __syncthreads();
  }
#pragma unroll
  for (int i = 0; i < 4; i++) {
    int mm = m0 + (ty << 2) + i;
#pragma unroll
    for (int j = 0; j < 4; j++) {
      int nn = n0 + (tx << 2) + j;
      float v = acc[i][j];
      if (bias) v += bias[nn];
      if (act == 1) v = 0.5f * v * (1.0f + erff(v * 0.70710678118654752f));
      if (res) v += res[(size_t)mm * N + nn];
      C[(size_t)mm * N + nn] = v;
    }
  }
}

// ---------------------------------------------------------------------------
// Attention: grid (S/64, NH, B), block 256. Flash-style fp32, online softmax.
// Q,K,V are [B*S, D] with head h at columns h*64..h*64+63.
// scores = (q . k) / 8 ; keys >= vlen[b] -> -1e6 ; fully-masked tiles skipped.
// ---------------------------------------------------------------------------
__global__ __launch_bounds__(256) void attn_kernel(
    const float* __restrict__ Q, const float* __restrict__ K,
    const float* __restrict__ V, const int* __restrict__ vlen,
    float* __restrict__ AO) {
  __shared__ float q_s[64][68];  // [d][row], pre-scaled by 0.125
  __shared__ float k_s[64][68];  // [d][key]
  __shared__ float v_s[64][68];  // [key][d]
  __shared__ float p_s[64][68];  // [key][row]
  int b = blockIdx.z, h = blockIdx.y, q0 = blockIdx.x * 64;
  int vl = vlen[b];
  int tx = threadIdx.x & 15, ty = threadIdx.x >> 4;

  {  // stage q (transposed, scaled)
    int r  = threadIdx.x >> 2;
    int dq = (threadIdx.x & 3) << 4;
    const float* qp = Q + ((size_t)(b * SS + q0 + r)) * DD + h * DH + dq;
#pragma unroll
    for (int i = 0; i < 4; i++) {
      float4 qv = *(const float4*)(qp + i * 4);
      q_s[dq + i * 4 + 0][r] = qv.x * 0.125f;
      q_s[dq + i * 4 + 1][r] = qv.y * 0.125f;
      q_s[dq + i * 4 + 2][r] = qv.z * 0.125f;
      q_s[dq + i * 4 + 3][r] = qv.w * 0.125f;
    }
  }

  float outv[4][4] = {};
  float mrun[4], lrun[4];
#pragma unroll
  for (int i = 0; i < 4; i++) { mrun[i] = -3e38f; lrun[i] = 0.0f; }

  int ntiles = (vl + 63) >> 6;
  if (ntiles > 16) ntiles = 16;

  for (int t = 0; t < ntiles; t++) {
    int kg0 = t * 64;
    {  // stage K (transposed) and V (direct)
      int kk = threadIdx.x >> 2;
      int dq = (threadIdx.x & 3) << 4;
      const float* kp = K + ((size_t)(b * SS + kg0 + kk)) * DD + h * DH + dq;
      const float* vp = V + ((size_t)(b * SS + kg0 + kk)) * DD + h * DH + dq;
#pragma unroll
      for (int i = 0; i < 4; i++) {
        float4 kv = *(const float4*)(kp + i * 4);
        k_s[dq + i * 4 + 0][kk] = kv.x;
        k_s[dq + i * 4 + 1][kk] = kv.y;
        k_s[dq + i * 4 + 2][kk] = kv.z;
        k_s[dq + i * 4 + 3][kk] = kv.w;
        *(float4*)(&v_s[kk][dq + i * 4]) = *(const float4*)(vp + i * 4);
      }
    }
    __syncthreads();

    // scores: 64 rows x 64 keys; thread -> rows ty*4+i, keys tx*4+j
    float sc[4][4] = {};
#pragma unroll
    for (int d = 0; d < 64; d++) {
      float qv[4], kv[4];
      *(float4*)qv = *(const float4*)(&q_s[d][ty << 2]);
      *(float4*)kv = *(const float4*)(&k_s[d][tx << 2]);
#pragma unroll
      for (int i = 0; i < 4; i++)
#pragma unroll
        for (int j = 0; j < 4; j++) sc[i][j] = fmaf(qv[i], kv[j], sc[i][j]);
    }
    // mask
#pragma unroll
    for (int j = 0; j < 4; j++) {
      int kg = kg0 + (tx << 2) + j;
      if (kg >= vl) {
#pragma unroll
        for (int i = 0; i < 4; i++) sc[i][j] = -1e6f;
      }
    }
    // online softmax per row; row-group = 16 lanes sharing ty
#pragma unroll
    for (int i = 0; i < 4; i++) {
      float mx = fmaxf(fmaxf(sc[i][0], sc[i][1]), fmaxf(sc[i][2], sc[i][3]));
      for (int off = 1; off < 16; off <<= 1) mx = fmaxf(mx, __shfl_xor(mx, off));
      float mnew  = fmaxf(mrun[i], mx);
      float alpha = expf(mrun[i] - mnew);
      float ls = 0.0f;
#pragma unroll
      for (int j = 0; j < 4; j++) {
        sc[i][j] = expf(sc[i][j] - mnew);
        ls += sc[i][j];
      }
      for (int off = 1; off < 16; off <<= 1) ls += __shfl_xor(ls, off);
      lrun[i] = lrun[i] * alpha + ls;
      mrun[i] = mnew;
#pragma unroll
      for (int j = 0; j < 4; j++) outv[i][j] *= alpha;
#pragma unroll
      for (int j = 0; j < 4; j++) p_s[(tx << 2) + j][(ty << 2) + i] = sc[i][j];
    }
    __syncthreads();

    // PV: out[row][d] += sum_k P[k][row] * V[k][d]
#pragma unroll
    for (int k = 0; k < 64; k++) {
      float pv[4], vv[4];
      *(float4*)pv = *(const float4*)(&p_s[k][ty << 2]);
      *(float4*)vv = *(const float4*)(&v_s[k][tx << 2]);
#pragma unroll
      for (int i = 0; i < 4; i++)
#pragma unroll
        for (int j = 0; j < 4; j++) outv[i][j] = fmaf(pv[i], vv[j], outv[i][j]);
    }
    __syncthreads();
  }

#pragma unroll
  for (int i = 0; i < 4; i++) {
    int row = q0 + (ty << 2) + i;
    float inv = 1.0f / lrun[i];
#pragma unroll
    for (int j = 0; j < 4; j++) {
      AO[((size_t)(b * SS + row)) * DD + h * DH + (tx << 2) + j] =
          outv[i][j] * inv;
    }
  }
}

// ---------------------------------------------------------------------------
extern "C" void kernel_launch(void* const* d_in, const int* in_sizes, int n_in,
                              void* d_out, int out_size, void* d_ws,
                              size_t ws_size, hipStream_t stream) {
  const float* X    = (const float*)d_in[0];
  const int*   vlen = (const int*)d_in[1];
  const float* ln1g = (const float*)d_in[2];
  const float* ln1b = (const float*)d_in[3];
  const float* Wq   = (const float*)d_in[4];
  const float* Wk   = (const float*)d_in[5];
  const float* Wv   = (const float*)d_in[6];
  const float* Wo   = (const float*)d_in[7];
  const float* ln2g = (const float*)d_in[8];
  const float* ln2b = (const float*)d_in[9];
  const float* W1   = (const float*)d_in[10];
  const float* b1   = (const float*)d_in[11];
  const float* W2   = (const float*)d_in[12];
  const float* b2   = (const float*)d_in[13];
  float* out = (float*)d_out;
  float* ws  = (float*)d_ws;

  const size_t NMD = (size_t)MM * DD;  // 4M floats
  float* h   = ws;            // [8192,512]
  float* Qb  = ws + 1 * NMD;  // [8192,512]
  float* Kb  = ws + 2 * NMD;
  float* Vb  = ws + 3 * NMD;
  float* AOb = ws + 4 * NMD;
  float* mid = Qb;            // [8192,2048] overlays Qb..AOb (all dead by then)
  float* h2  = h;             // overlays h (dead after QKV)

  dim3 blk(256);

  // 1. h = LN1(X)
  ln_kernel<<<dim3(MM / 4), blk, 0, stream>>>(X, ln1g, ln1b, h);
  // 2. Q,K,V projections
  {
    dim3 g(DD / 64, MM / 64);
    gemm_kernel<<<g, blk, 0, stream>>>(h, Wq, nullptr, nullptr, Qb, MM, DD, DD, 0);
    gemm_kernel<<<g, blk, 0, stream>>>(h, Wk, nullptr, nullptr, Kb, MM, DD, DD, 0);
    gemm_kernel<<<g, blk, 0, stream>>>(h, Wv, nullptr, nullptr, Vb, MM, DD, DD, 0);
  }
  // 3. attention
  attn_kernel<<<dim3(SS / 64, NH, BB), blk, 0, stream>>>(Qb, Kb, Vb, vlen, AOb);
  // 4. X1 = X + AO @ Wo  -> d_out
  gemm_kernel<<<dim3(DD / 64, MM / 64), blk, 0, stream>>>(AOb, Wo, nullptr, X,
                                                          out, MM, DD, DD, 0);
  // 5. h2 = LN2(X1)
  ln_kernel<<<dim3(MM / 4), blk, 0, stream>>>(out, ln2g, ln2b, h2);
  // 6. mid = gelu(h2 @ W1 + b1)
  gemm_kernel<<<dim3(FF / 64, MM / 64), blk, 0, stream>>>(h2, W1, b1, nullptr,
                                                          mid, MM, FF, DD, 1);
  // 7. out = X1 + mid @ W2 + b2   (residual read from d_out in-place)
  gemm_kernel<<<dim3(DD / 64, MM / 64), blk, 0, stream>>>(mid, W2, b2, out,
                                                          out, MM, DD, FF, 0);
}

// Round 2
// 248.033 us; speedup vs baseline: 4.2036x; 4.2036x over previous
//
#include <hip/hip_runtime.h>
#include <math.h>

#define BB 8
#define SS 1024
#define DD 512
#define FF 2048
#define NH 8
#define MM (BB * SS)     // 8192 rows
#define LDQKV 1536       // QKV buffer row stride (Q|K|V concatenated)

using bf8 = __attribute__((ext_vector_type(8))) short;   // 8 x bf16 (4 VGPR)
using f4  = __attribute__((ext_vector_type(4))) float;   // MFMA accumulator

#define AS1 __attribute__((address_space(1)))
#define AS3 __attribute__((address_space(3)))

__device__ __forceinline__ void gload16(const void* g, void* l) {
  // async global->LDS, 16B per lane; LDS dest = wave-uniform base + lane*16
  __builtin_amdgcn_global_load_lds((AS1 const void*)g, (AS3 void*)l, 16, 0, 0);
}

__device__ __forceinline__ unsigned short f2b(float f) {  // fp32 -> bf16 RNE
  union { float f; unsigned u; } v; v.f = f;
  unsigned r = v.u + 0x7fffu + ((v.u >> 16) & 1u);
  return (unsigned short)(r >> 16);
}

// ---------------------------------------------------------------------------
// LayerNorm fp32 -> bf16. One wave per row of 512. grid = MM/4, block = 256.
// ---------------------------------------------------------------------------
__global__ __launch_bounds__(256) void ln_bf16(const float* __restrict__ x,
                                               const float* __restrict__ g,
                                               const float* __restrict__ bta,
                                               unsigned short* __restrict__ out) {
  int wave = threadIdx.x >> 6, lane = threadIdx.x & 63;
  int row = (blockIdx.x << 2) + wave;
  const float* xr = x + (size_t)row * DD;
  int base = lane << 3;
  float4 v0 = *(const float4*)(xr + base);
  float4 v1 = *(const float4*)(xr + base + 4);
  float s  = v0.x + v0.y + v0.z + v0.w + v1.x + v1.y + v1.z + v1.w;
  float sq = v0.x*v0.x + v0.y*v0.y + v0.z*v0.z + v0.w*v0.w
           + v1.x*v1.x + v1.y*v1.y + v1.z*v1.z + v1.w*v1.w;
  for (int m = 32; m; m >>= 1) { s += __shfl_xor(s, m); sq += __shfl_xor(sq, m); }
  float mu  = s * (1.0f / DD);
  float var = sq * (1.0f / DD) - mu * mu;
  float rs  = rsqrtf(var + 1e-5f);
  float xv[8], go[8], bo[8];
  *(float4*)(xv) = v0; *(float4*)(xv + 4) = v1;
  *(float4*)(go)     = *(const float4*)(g + base);
  *(float4*)(go + 4) = *(const float4*)(g + base + 4);
  *(float4*)(bo)     = *(const float4*)(bta + base);
  *(float4*)(bo + 4) = *(const float4*)(bta + base + 4);
  union { unsigned short u[8]; uint4 v; } ov;
#pragma unroll
  for (int i = 0; i < 8; i++) ov.u[i] = f2b((xv[i] - mu) * rs * go[i] + bo[i]);
  *(uint4*)(out + (size_t)row * DD + base) = ov.v;
}

// ---------------------------------------------------------------------------
// Transpose + fp32->bf16: in [K][N] fp32 -> out [N][K] bf16. grid(N/32, K/32).
// ---------------------------------------------------------------------------
__global__ __launch_bounds__(256) void tconv(const float* __restrict__ in,
                                             unsigned short* __restrict__ outp,
                                             int K, int N) {
  __shared__ float tile[32][33];
  int n0 = blockIdx.x << 5, k0 = blockIdx.y << 5;
  int c = threadIdx.x & 31, r = threadIdx.x >> 5;  // r = 0..7
#pragma unroll
  for (int i = 0; i < 4; i++)
    tile[r + 8 * i][c] = in[(size_t)(k0 + r + 8 * i) * N + n0 + c];
  __syncthreads();
#pragma unroll
  for (int i = 0; i < 4; i++)
    outp[(size_t)(n0 + r + 8 * i) * K + k0 + c] = f2b(tile[c][r + 8 * i]);
}

// ---------------------------------------------------------------------------
// bf16 MFMA GEMM: C[M,N] = epi(A[M,K] @ Bt[N,K]^T)
// 128x128 tile, BK=32, 256 threads (4 waves, 2x2 of 64x64).
// LDS [row][32] bf16 linear rows; 16B slot-swizzle s^=row&3 applied on the
// global SOURCE of global_load_lds and on the ds_read address (rule #21).
// epi: +bias (fp32), act(1=gelu exact), +res (fp32), out fp32 or bf16.
// ---------------------------------------------------------------------------
__global__ __launch_bounds__(256) void gemm_bf16(
    const unsigned short* __restrict__ A,   // [M][K] bf16
    const unsigned short* __restrict__ Bt,  // [N][K] bf16
    const float* __restrict__ bias,         // [N] or null
    const float* __restrict__ res,          // [M][N] fp32 or null
    float* __restrict__ Cf,                 // fp32 out (or null)
    unsigned short* __restrict__ Cb,        // bf16 out (or null)
    int M, int N, int K, int act) {
  __shared__ unsigned short As[128 * 32];   // 8 KB
  __shared__ unsigned short Bs[128 * 32];   // 8 KB
  int tid = threadIdx.x, wid = tid >> 6, lane = tid & 63;
  int m0 = blockIdx.y << 7, n0 = blockIdx.x << 7;
  int wm = (wid >> 1) << 6, wn = (wid & 1) << 6;
  int r4 = lane & 15, ksl = lane >> 4;

  // staging: chunk = 1KB = 16 rows x 32 cols; wave w owns chunks 2w, 2w+1
  int srow = lane >> 2;                     // row within chunk (0..15)
  int gs   = (lane & 3) ^ (srow & 3);       // inverse-swizzled global slot
  const unsigned short* aSrc = A  + (size_t)(m0 + wid * 32 + srow) * K + gs * 8;
  const unsigned short* bSrc = Bt + (size_t)(n0 + wid * 32 + srow) * K + gs * 8;
  unsigned short* aDst = As + wid * 1024;   // wave-uniform
  unsigned short* bDst = Bs + wid * 1024;
  size_t rstep = (size_t)16 * K;

  f4 acc[4][4];
#pragma unroll
  for (int i = 0; i < 4; i++)
#pragma unroll
    for (int j = 0; j < 4; j++) acc[i][j] = (f4){0.f, 0.f, 0.f, 0.f};

  for (int k0 = 0; k0 < K; k0 += 32) {
    gload16(aSrc + k0,         aDst);
    gload16(aSrc + k0 + rstep, aDst + 512);
    gload16(bSrc + k0,         bDst);
    gload16(bSrc + k0 + rstep, bDst + 512);
    __syncthreads();  // compiler drains vmcnt before barrier
    bf8 af[4], bfr[4];
#pragma unroll
    for (int mi = 0; mi < 4; mi++) {
      int r = wm + mi * 16 + r4;
      af[mi] = *(const bf8*)((const char*)As + (r << 6) + ((ksl ^ (r & 3)) << 4));
    }
#pragma unroll
    for (int ni = 0; ni < 4; ni++) {
      int r = wn + ni * 16 + r4;
      bfr[ni] = *(const bf8*)((const char*)Bs + (r << 6) + ((ksl ^ (r & 3)) << 4));
    }
#pragma unroll
    for (int mi = 0; mi < 4; mi++)
#pragma unroll
      for (int ni = 0; ni < 4; ni++)
        acc[mi][ni] = __builtin_amdgcn_mfma_f32_16x16x32_bf16(
            af[mi], bfr[ni], acc[mi][ni], 0, 0, 0);
    __syncthreads();
  }

  int rq = (lane >> 4) << 2;
#pragma unroll
  for (int ni = 0; ni < 4; ni++) {
    int col = n0 + wn + ni * 16 + r4;
    float bv = bias ? bias[col] : 0.0f;
#pragma unroll
    for (int mi = 0; mi < 4; mi++) {
#pragma unroll
      for (int j = 0; j < 4; j++) {
        int row = m0 + wm + mi * 16 + rq + j;
        float v = acc[mi][ni][j] + bv;
        if (act) v = 0.5f * v * (1.0f + erff(v * 0.70710678118654752f));
        if (res) v += res[(size_t)row * N + col];
        if (Cf) Cf[(size_t)row * N + col] = v;
        else    Cb[(size_t)row * N + col] = f2b(v);
      }
    }
  }
}

// ---------------------------------------------------------------------------
// Flash attention, bf16 MFMA. grid (S/64, NH, B), block 256 (4 waves).
// Wave w owns q-rows w*16..w*16+15 of the 64-row Q tile.
// All LDS tiles are 64 rows x 64 bf16 (128B rows, 8 slots), slot^=(row&7).
// ---------------------------------------------------------------------------
__global__ __launch_bounds__(256) void attn_mfma(
    const unsigned short* __restrict__ QKV,  // [B*S][1536]
    const int* __restrict__ vlen,
    unsigned short* __restrict__ AO) {       // [B*S][512]
  __shared__ unsigned short Qs[64 * 64];
  __shared__ unsigned short Ks[64 * 64];
  __shared__ unsigned short Vt[64 * 64];     // transposed: [d][k]
  __shared__ unsigned short Ps[64 * 64];     // [q][k]
  int b = blockIdx.z, h = blockIdx.y, q0 = blockIdx.x << 6;
  int tid = threadIdx.x, wid = tid >> 6, lane = tid & 63;
  int vl = vlen[b];
  int r4 = lane & 15, ksl = lane >> 4;

  // ---- stage Q (2 chunks of 1KB per wave; chunk = 8 rows of 128B)
  int srow = lane >> 3;                 // 0..7
  int gs = (lane & 7) ^ srow;           // inverse-swizzled 16B slot
  {
    const unsigned short* qsrc =
        QKV + (size_t)(b * SS + q0 + wid * 16 + srow) * LDQKV + h * 64 + gs * 8;
    gload16(qsrc, Qs + wid * 1024);
    gload16(qsrc + (size_t)8 * LDQKV, Qs + wid * 1024 + 512);
  }
  const unsigned short* kbase =
      QKV + (size_t)(b * SS + wid * 16 + srow) * LDQKV + DD + h * 64 + gs * 8;
  int vp = tid & 31, vdg = (tid >> 5) << 3;
  const unsigned short* vbase =
      QKV + (size_t)(b * SS + 2 * vp) * LDQKV + 2 * DD + h * 64 + vdg;

  f4 o[4];
#pragma unroll
  for (int i = 0; i < 4; i++) o[i] = (f4){0.f, 0.f, 0.f, 0.f};
  float mrun[4], lrun[4];
#pragma unroll
  for (int j = 0; j < 4; j++) { mrun[j] = -3e38f; lrun[j] = 0.0f; }

  int ntiles = (vl + 63) >> 6;
  if (ntiles > 16) ntiles = 16;

  for (int t = 0; t < ntiles; t++) {
    int kg0 = t << 6;
    // stage K via global_load_lds
    const unsigned short* ks = kbase + (size_t)kg0 * LDQKV;
    gload16(ks, Ks + wid * 1024);
    gload16(ks + (size_t)8 * LDQKV, Ks + wid * 1024 + 512);
    // stage V transposed: pack key-pairs into u32, swizzled ds_write_b32
    {
      const unsigned short* v0 = vbase + (size_t)kg0 * LDQKV;
      const unsigned short* v1 = v0 + LDQKV;
      unsigned short va[8], vb[8];
      *(uint4*)va = *(const uint4*)v0;
      *(uint4*)vb = *(const uint4*)v1;
#pragma unroll
      for (int i = 0; i < 8; i++) {
        int d = vdg + i;
        unsigned val = (unsigned)va[i] | ((unsigned)vb[i] << 16);
        int byte = (d << 7) + (((vp >> 2) ^ (d & 7)) << 4) + ((vp & 3) << 2);
        *(unsigned*)((char*)Vt + byte) = val;
      }
    }
    __syncthreads();

    // ---- S = Q @ K^T  (rows: this wave's 16 q; cols: 64 keys)
    f4 s[4];
#pragma unroll
    for (int i = 0; i < 4; i++) s[i] = (f4){0.f, 0.f, 0.f, 0.f};
#pragma unroll
    for (int k2 = 0; k2 < 2; k2++) {
      int slot = (k2 << 2) + ksl;
      int qr = (wid << 4) + r4;
      bf8 aq = *(const bf8*)((const char*)Qs + (qr << 7) + ((slot ^ (qr & 7)) << 4));
#pragma unroll
      for (int ni = 0; ni < 4; ni++) {
        int kr = (ni << 4) + r4;
        bf8 bk = *(const bf8*)((const char*)Ks + (kr << 7) + ((slot ^ (kr & 7)) << 4));
        s[ni] = __builtin_amdgcn_mfma_f32_16x16x32_bf16(aq, bk, s[ni], 0, 0, 0);
      }
    }

    // ---- online softmax (rows in-register; 16-lane shfl reduce)
#pragma unroll
    for (int j = 0; j < 4; j++) {
      int qr = (wid << 4) + ((lane >> 4) << 2) + j;
      float sv[4], mx = -3e38f;
#pragma unroll
      for (int ni = 0; ni < 4; ni++) {
        float v = s[ni][j] * 0.125f;                       // 1/sqrt(64)
        if (kg0 + (ni << 4) + r4 >= vl) v = -1e6f;         // masked_softmax
        sv[ni] = v;
        mx = fmaxf(mx, v);
      }
#pragma unroll
      for (int m2 = 1; m2 < 16; m2 <<= 1) mx = fmaxf(mx, __shfl_xor(mx, m2));
      float mnew = fmaxf(mrun[j], mx);
      float al = __expf(mrun[j] - mnew);
      float ls = 0.0f;
      unsigned short pb[4];
#pragma unroll
      for (int ni = 0; ni < 4; ni++) {
        float p = __expf(sv[ni] - mnew);
        ls += p;
        pb[ni] = f2b(p);
      }
#pragma unroll
      for (int m2 = 1; m2 < 16; m2 <<= 1) ls += __shfl_xor(ls, m2);
      lrun[j] = lrun[j] * al + ls;
      mrun[j] = mnew;
#pragma unroll
      for (int ni = 0; ni < 4; ni++) {
        int kc = (ni << 4) + r4;
        int byte = (qr << 7) + (((kc >> 3) ^ (qr & 7)) << 4) + ((kc & 7) << 1);
        *(unsigned short*)((char*)Ps + byte) = pb[ni];
        o[ni][j] *= al;
      }
    }

    // ---- O += P @ V   (A = P rows of this wave; B cols = d via Vt)
#pragma unroll
    for (int k2 = 0; k2 < 2; k2++) {
      int slot = (k2 << 2) + ksl;
      int qr = (wid << 4) + r4;
      bf8 ap = *(const bf8*)((const char*)Ps + (qr << 7) + ((slot ^ (qr & 7)) << 4));
#pragma unroll
      for (int ni = 0; ni < 4; ni++) {
        int dr = (ni << 4) + r4;
        bf8 bv = *(const bf8*)((const char*)Vt + (dr << 7) + ((slot ^ (dr & 7)) << 4));
        o[ni] = __builtin_amdgcn_mfma_f32_16x16x32_bf16(ap, bv, o[ni], 0, 0, 0);
      }
    }
    __syncthreads();  // before next tile overwrites Ks/Vt
  }

  float inv[4];
#pragma unroll
  for (int j = 0; j < 4; j++) inv[j] = 1.0f / lrun[j];
#pragma unroll
  for (int ni = 0; ni < 4; ni++) {
#pragma unroll
    for (int j = 0; j < 4; j++) {
      int qr = (wid << 4) + ((lane >> 4) << 2) + j;
      int d = (ni << 4) + r4;
      AO[(size_t)(b * SS + q0 + qr) * DD + h * 64 + d] = f2b(o[ni][j] * inv[j]);
    }
  }
}

// ---------------------------------------------------------------------------
extern "C" void kernel_launch(void* const* d_in, const int* in_sizes, int n_in,
                              void* d_out, int out_size, void* d_ws,
                              size_t ws_size, hipStream_t stream) {
  const float* X    = (const float*)d_in[0];
  const int*   vln  = (const int*)d_in[1];
  const float* ln1g = (const float*)d_in[2];
  const float* ln1b = (const float*)d_in[3];
  const float* Wq   = (const float*)d_in[4];
  const float* Wk   = (const float*)d_in[5];
  const float* Wv   = (const float*)d_in[6];
  const float* Wo   = (const float*)d_in[7];
  const float* ln2g = (const float*)d_in[8];
  const float* ln2b = (const float*)d_in[9];
  const float* W1   = (const float*)d_in[10];
  const float* b1   = (const float*)d_in[11];
  const float* W2   = (const float*)d_in[12];
  const float* b2   = (const float*)d_in[13];
  float* out = (float*)d_out;

  unsigned short* ws = (unsigned short*)d_ws;
  unsigned short* h     = ws;                          // 8192x512
  unsigned short* QKVb  = h     + (size_t)MM * DD;     // 8192x1536
  unsigned short* AOb   = QKVb  + (size_t)MM * LDQKV;  // 8192x512
  unsigned short* mid   = AOb   + (size_t)MM * DD;     // 8192x2048
  unsigned short* Wqkvt = mid   + (size_t)MM * FF;     // 1536x512
  unsigned short* Wot   = Wqkvt + (size_t)3 * DD * DD; // 512x512
  unsigned short* W1t   = Wot   + (size_t)DD * DD;     // 2048x512
  unsigned short* W2t   = W1t   + (size_t)FF * DD;     // 512x2048

  dim3 blk(256);

  // weight prep: transpose + convert to bf16 [N][K]
  tconv<<<dim3(16, 16), blk, 0, stream>>>(Wq, Wqkvt, DD, DD);
  tconv<<<dim3(16, 16), blk, 0, stream>>>(Wk, Wqkvt + (size_t)DD * DD, DD, DD);
  tconv<<<dim3(16, 16), blk, 0, stream>>>(Wv, Wqkvt + (size_t)2 * DD * DD, DD, DD);
  tconv<<<dim3(16, 16), blk, 0, stream>>>(Wo, Wot, DD, DD);
  tconv<<<dim3(64, 16), blk, 0, stream>>>(W1, W1t, DD, FF);
  tconv<<<dim3(16, 64), blk, 0, stream>>>(W2, W2t, FF, DD);

  // 1. h = bf16(LN1(X))
  ln_bf16<<<dim3(MM / 4), blk, 0, stream>>>(X, ln1g, ln1b, h);
  // 2. QKV = h @ [Wq|Wk|Wv]  (bf16 out)
  gemm_bf16<<<dim3(LDQKV / 128, MM / 128), blk, 0, stream>>>(
      h, Wqkvt, nullptr, nullptr, nullptr, QKVb, MM, LDQKV, DD, 0);
  // 3. attention
  attn_mfma<<<dim3(SS / 64, NH, BB), blk, 0, stream>>>(QKVb, vln, AOb);
  // 4. out = X + AO @ Wo   (fp32)
  gemm_bf16<<<dim3(DD / 128, MM / 128), blk, 0, stream>>>(
      AOb, Wot, nullptr, X, out, nullptr, MM, DD, DD, 0);
  // 5. h2 = bf16(LN2(out))  (overlays h)
  ln_bf16<<<dim3(MM / 4), blk, 0, stream>>>(out, ln2g, ln2b, h);
  // 6. mid = bf16(gelu(h2 @ W1 + b1))
  gemm_bf16<<<dim3(FF / 128, MM / 128), blk, 0, stream>>>(
      h, W1t, b1, nullptr, nullptr, mid, MM, FF, DD, 1);
  // 7. out = out + mid @ W2 + b2  (fp32, in-place residual)
  gemm_bf16<<<dim3(DD / 128, MM / 128), blk, 0, stream>>>(
      mid, W2t, b2, out, out, nullptr, MM, DD, FF, 0);
}

// Round 3
// 213.864 us; speedup vs baseline: 4.8752x; 1.1598x over previous
//
#include <hip/hip_runtime.h>
#include <math.h>

#define BB 8
#define SS 1024
#define DD 512
#define FF 2048
#define NH 8
#define MM (BB * SS)     // 8192 rows
#define LDQKV 1536       // QKV buffer row stride (Q|K|V concatenated)

using bf8 = __attribute__((ext_vector_type(8))) short;   // 8 x bf16 (4 VGPR)
using f4  = __attribute__((ext_vector_type(4))) float;   // MFMA accumulator

#define AS1 __attribute__((address_space(1)))
#define AS3 __attribute__((address_space(3)))

__device__ __forceinline__ void gload16(const void* g, void* l) {
  // async global->LDS, 16B per lane; LDS dest = wave-uniform base + lane*16
  __builtin_amdgcn_global_load_lds((AS1 const void*)g, (AS3 void*)l, 16, 0, 0);
}

__device__ __forceinline__ unsigned short f2b(float f) {  // fp32 -> bf16 RNE
  union { float f; unsigned u; } v; v.f = f;
  unsigned r = v.u + 0x7fffu + ((v.u >> 16) & 1u);
  return (unsigned short)(r >> 16);
}

// ---------------------------------------------------------------------------
// LayerNorm fp32 -> bf16. One wave per row of 512. grid = MM/4, block = 256.
// ---------------------------------------------------------------------------
__global__ __launch_bounds__(256) void ln_bf16(const float* __restrict__ x,
                                               const float* __restrict__ g,
                                               const float* __restrict__ bta,
                                               unsigned short* __restrict__ out) {
  int wave = threadIdx.x >> 6, lane = threadIdx.x & 63;
  int row = (blockIdx.x << 2) + wave;
  const float* xr = x + (size_t)row * DD;
  int base = lane << 3;
  float4 v0 = *(const float4*)(xr + base);
  float4 v1 = *(const float4*)(xr + base + 4);
  float s  = v0.x + v0.y + v0.z + v0.w + v1.x + v1.y + v1.z + v1.w;
  float sq = v0.x*v0.x + v0.y*v0.y + v0.z*v0.z + v0.w*v0.w
           + v1.x*v1.x + v1.y*v1.y + v1.z*v1.z + v1.w*v1.w;
  for (int m = 32; m; m >>= 1) { s += __shfl_xor(s, m); sq += __shfl_xor(sq, m); }
  float mu  = s * (1.0f / DD);
  float var = sq * (1.0f / DD) - mu * mu;
  float rs  = rsqrtf(var + 1e-5f);
  float xv[8], go[8], bo[8];
  *(float4*)(xv) = v0; *(float4*)(xv + 4) = v1;
  *(float4*)(go)     = *(const float4*)(g + base);
  *(float4*)(go + 4) = *(const float4*)(g + base + 4);
  *(float4*)(bo)     = *(const float4*)(bta + base);
  *(float4*)(bo + 4) = *(const float4*)(bta + base + 4);
  union { unsigned short u[8]; uint4 v; } ov;
#pragma unroll
  for (int i = 0; i < 8; i++) ov.u[i] = f2b((xv[i] - mu) * rs * go[i] + bo[i]);
  *(uint4*)(out + (size_t)row * DD + base) = ov.v;
}

// ---------------------------------------------------------------------------
// Transpose + fp32->bf16: in [K][N] fp32 -> out [N][K] bf16. grid(N/32, K/32).
// ---------------------------------------------------------------------------
__global__ __launch_bounds__(256) void tconv(const float* __restrict__ in,
                                             unsigned short* __restrict__ outp,
                                             int K, int N) {
  __shared__ float tile[32][33];
  int n0 = blockIdx.x << 5, k0 = blockIdx.y << 5;
  int c = threadIdx.x & 31, r = threadIdx.x >> 5;  // r = 0..7
#pragma unroll
  for (int i = 0; i < 4; i++)
    tile[r + 8 * i][c] = in[(size_t)(k0 + r + 8 * i) * N + n0 + c];
  __syncthreads();
#pragma unroll
  for (int i = 0; i < 4; i++)
    outp[(size_t)(n0 + r + 8 * i) * K + k0 + c] = f2b(tile[c][r + 8 * i]);
}

// ---------------------------------------------------------------------------
// bf16 MFMA GEMM, templated tile: C[M,N] = epi(A[M,K] @ Bt[N,K]^T)
// BK=64, double-buffered LDS, T3-minimal 2-phase (stage next, compute cur,
// one barrier per K-step). 256 threads = 4 waves (2x2), wave = (BM/2)x(BN/2).
// LDS rows are 128B = 8 x 16B slots, slot-swizzle slot^=(row&7); applied on
// the global SOURCE of global_load_lds and on the ds_read address (rule #21).
// epi: +bias (fp32), ACT(1=gelu exact), +res (fp32), out fp32 or bf16.
// ---------------------------------------------------------------------------
template <int BM, int BN, int ACT>
__global__ __launch_bounds__(256) void gemm_t(
    const unsigned short* __restrict__ A,   // [M][K] bf16
    const unsigned short* __restrict__ Bt,  // [N][K] bf16
    const float* __restrict__ bias,         // [N] or null
    const float* __restrict__ res,          // [M][N] fp32 or null
    float* __restrict__ Cf,                 // fp32 out (or null)
    unsigned short* __restrict__ Cb,        // bf16 out (or null)
    int M, int N, int K) {
  constexpr int WM = BM / 2, WN = BN / 2;
  constexpr int FM = WM / 16, FN = WN / 16;
  constexpr int ACH = BM / 32, BCH = BN / 32;  // 1KB chunks per wave
  __shared__ unsigned short As[2][BM * 64];
  __shared__ unsigned short Bs[2][BN * 64];
  int tid = threadIdx.x, wid = tid >> 6, lane = tid & 63;
  int m0 = blockIdx.y * BM, n0 = blockIdx.x * BN;
  int wm = (wid >> 1) * WM, wn = (wid & 1) * WN;
  int r4 = lane & 15, ksl = lane >> 4;
  int srow = lane >> 3, gs = (lane & 7) ^ srow;  // inverse-swizzled 16B slot

  const unsigned short* aBase =
      A + (size_t)(m0 + wid * (ACH * 8) + srow) * K + gs * 8;
  const unsigned short* bBase =
      Bt + (size_t)(n0 + wid * (BCH * 8) + srow) * K + gs * 8;

  f4 acc[FM][FN];
#pragma unroll
  for (int i = 0; i < FM; i++)
#pragma unroll
    for (int j = 0; j < FN; j++) acc[i][j] = (f4){0.f, 0.f, 0.f, 0.f};

  auto STAGE = [&](int buf, int k0) {
#pragma unroll
    for (int i = 0; i < ACH; i++)
      gload16(aBase + (size_t)i * 8 * K + k0, &As[buf][(wid * ACH + i) * 512]);
#pragma unroll
    for (int i = 0; i < BCH; i++)
      gload16(bBase + (size_t)i * 8 * K + k0, &Bs[buf][(wid * BCH + i) * 512]);
  };

  int nt = K >> 6;
  STAGE(0, 0);
  __syncthreads();
  int cur = 0;
  for (int t = 0; t < nt; t++) {
    if (t + 1 < nt) STAGE(cur ^ 1, (t + 1) << 6);  // prefetch next K-tile
#pragma unroll
    for (int k2 = 0; k2 < 2; k2++) {
      bf8 af[FM], bfr[FN];
#pragma unroll
      for (int mi = 0; mi < FM; mi++) {
        int r = wm + mi * 16 + r4;
        af[mi] = *(const bf8*)((const char*)&As[cur][0] + r * 128 +
                               (((k2 * 4 + ksl) ^ (r & 7)) << 4));
      }
#pragma unroll
      for (int ni = 0; ni < FN; ni++) {
        int r = wn + ni * 16 + r4;
        bfr[ni] = *(const bf8*)((const char*)&Bs[cur][0] + r * 128 +
                                (((k2 * 4 + ksl) ^ (r & 7)) << 4));
      }
#pragma unroll
      for (int mi = 0; mi < FM; mi++)
#pragma unroll
        for (int ni = 0; ni < FN; ni++)
          acc[mi][ni] = __builtin_amdgcn_mfma_f32_16x16x32_bf16(
              af[mi], bfr[ni], acc[mi][ni], 0, 0, 0);
    }
    __syncthreads();  // drains vmcnt of prefetch + frees cur for next stage
    cur ^= 1;
  }

  int rq = (lane >> 4) << 2;
#pragma unroll
  for (int ni = 0; ni < FN; ni++) {
    int col = n0 + wn + ni * 16 + r4;
    float bv = bias ? bias[col] : 0.0f;
#pragma unroll
    for (int mi = 0; mi < FM; mi++) {
#pragma unroll
      for (int j = 0; j < 4; j++) {
        int row = m0 + wm + mi * 16 + rq + j;
        float v = acc[mi][ni][j] + bv;
        if (ACT) v = 0.5f * v * (1.0f + erff(v * 0.70710678118654752f));
        if (res) v += res[(size_t)row * N + col];
        if (Cf) Cf[(size_t)row * N + col] = v;
        else    Cb[(size_t)row * N + col] = f2b(v);
      }
    }
  }
}

// ---------------------------------------------------------------------------
// Flash attention, bf16 MFMA. grid (S/64, NH, B), block 256 (4 waves).
// Wave w owns q-rows w*16..w*16+15 of the 64-row Q tile.
// All LDS tiles are 64 rows x 64 bf16 (128B rows, 8 slots), slot^=(row&7).
// ---------------------------------------------------------------------------
__global__ __launch_bounds__(256) void attn_mfma(
    const unsigned short* __restrict__ QKV,  // [B*S][1536]
    const int* __restrict__ vlen,
    unsigned short* __restrict__ AO) {       // [B*S][512]
  __shared__ unsigned short Qs[64 * 64];
  __shared__ unsigned short Ks[64 * 64];
  __shared__ unsigned short Vt[64 * 64];     // transposed: [d][k]
  __shared__ unsigned short Ps[64 * 64];     // [q][k]
  int b = blockIdx.z, h = blockIdx.y, q0 = blockIdx.x << 6;
  int tid = threadIdx.x, wid = tid >> 6, lane = tid & 63;
  int vl = vlen[b];
  int r4 = lane & 15, ksl = lane >> 4;

  // ---- stage Q (2 chunks of 1KB per wave; chunk = 8 rows of 128B)
  int srow = lane >> 3;                 // 0..7
  int gs = (lane & 7) ^ srow;           // inverse-swizzled 16B slot
  {
    const unsigned short* qsrc =
        QKV + (size_t)(b * SS + q0 + wid * 16 + srow) * LDQKV + h * 64 + gs * 8;
    gload16(qsrc, Qs + wid * 1024);
    gload16(qsrc + (size_t)8 * LDQKV, Qs + wid * 1024 + 512);
  }
  const unsigned short* kbase =
      QKV + (size_t)(b * SS + wid * 16 + srow) * LDQKV + DD + h * 64 + gs * 8;
  int vp = tid & 31, vdg = (tid >> 5) << 3;
  const unsigned short* vbase =
      QKV + (size_t)(b * SS + 2 * vp) * LDQKV + 2 * DD + h * 64 + vdg;

  f4 o[4];
#pragma unroll
  for (int i = 0; i < 4; i++) o[i] = (f4){0.f, 0.f, 0.f, 0.f};
  float mrun[4], lrun[4];
#pragma unroll
  for (int j = 0; j < 4; j++) { mrun[j] = -3e38f; lrun[j] = 0.0f; }

  int ntiles = (vl + 63) >> 6;
  if (ntiles > 16) ntiles = 16;

  for (int t = 0; t < ntiles; t++) {
    int kg0 = t << 6;
    // stage K via global_load_lds
    const unsigned short* ks = kbase + (size_t)kg0 * LDQKV;
    gload16(ks, Ks + wid * 1024);
    gload16(ks + (size_t)8 * LDQKV, Ks + wid * 1024 + 512);
    // stage V transposed: pack key-pairs into u32, swizzled ds_write_b32
    {
      const unsigned short* v0 = vbase + (size_t)kg0 * LDQKV;
      const unsigned short* v1 = v0 + LDQKV;
      unsigned short va[8], vb[8];
      *(uint4*)va = *(const uint4*)v0;
      *(uint4*)vb = *(const uint4*)v1;
#pragma unroll
      for (int i = 0; i < 8; i++) {
        int d = vdg + i;
        unsigned val = (unsigned)va[i] | ((unsigned)vb[i] << 16);
        int byte = (d << 7) + (((vp >> 2) ^ (d & 7)) << 4) + ((vp & 3) << 2);
        *(unsigned*)((char*)Vt + byte) = val;
      }
    }
    __syncthreads();

    // ---- S = Q @ K^T  (rows: this wave's 16 q; cols: 64 keys)
    f4 s[4];
#pragma unroll
    for (int i = 0; i < 4; i++) s[i] = (f4){0.f, 0.f, 0.f, 0.f};
#pragma unroll
    for (int k2 = 0; k2 < 2; k2++) {
      int slot = (k2 << 2) + ksl;
      int qr = (wid << 4) + r4;
      bf8 aq = *(const bf8*)((const char*)Qs + (qr << 7) + ((slot ^ (qr & 7)) << 4));
#pragma unroll
      for (int ni = 0; ni < 4; ni++) {
        int kr = (ni << 4) + r4;
        bf8 bk = *(const bf8*)((const char*)Ks + (kr << 7) + ((slot ^ (kr & 7)) << 4));
        s[ni] = __builtin_amdgcn_mfma_f32_16x16x32_bf16(aq, bk, s[ni], 0, 0, 0);
      }
    }

    // ---- online softmax (rows in-register; 16-lane shfl reduce)
#pragma unroll
    for (int j = 0; j < 4; j++) {
      int qr = (wid << 4) + ((lane >> 4) << 2) + j;
      float sv[4], mx = -3e38f;
#pragma unroll
      for (int ni = 0; ni < 4; ni++) {
        float v = s[ni][j] * 0.125f;                       // 1/sqrt(64)
        if (kg0 + (ni << 4) + r4 >= vl) v = -1e6f;         // masked_softmax
        sv[ni] = v;
        mx = fmaxf(mx, v);
      }
#pragma unroll
      for (int m2 = 1; m2 < 16; m2 <<= 1) mx = fmaxf(mx, __shfl_xor(mx, m2));
      float mnew = fmaxf(mrun[j], mx);
      float al = __expf(mrun[j] - mnew);
      float ls = 0.0f;
      unsigned short pb[4];
#pragma unroll
      for (int ni = 0; ni < 4; ni++) {
        float p = __expf(sv[ni] - mnew);
        ls += p;
        pb[ni] = f2b(p);
      }
#pragma unroll
      for (int m2 = 1; m2 < 16; m2 <<= 1) ls += __shfl_xor(ls, m2);
      lrun[j] = lrun[j] * al + ls;
      mrun[j] = mnew;
#pragma unroll
      for (int ni = 0; ni < 4; ni++) {
        int kc = (ni << 4) + r4;
        int byte = (qr << 7) + (((kc >> 3) ^ (qr & 7)) << 4) + ((kc & 7) << 1);
        *(unsigned short*)((char*)Ps + byte) = pb[ni];
        o[ni][j] *= al;
      }
    }

    // ---- O += P @ V   (A = P rows of this wave; B cols = d via Vt)
#pragma unroll
    for (int k2 = 0; k2 < 2; k2++) {
      int slot = (k2 << 2) + ksl;
      int qr = (wid << 4) + r4;
      bf8 ap = *(const bf8*)((const char*)Ps + (qr << 7) + ((slot ^ (qr & 7)) << 4));
#pragma unroll
      for (int ni = 0; ni < 4; ni++) {
        int dr = (ni << 4) + r4;
        bf8 bv = *(const bf8*)((const char*)Vt + (dr << 7) + ((slot ^ (dr & 7)) << 4));
        o[ni] = __builtin_amdgcn_mfma_f32_16x16x32_bf16(ap, bv, o[ni], 0, 0, 0);
      }
    }
    __syncthreads();  // before next tile overwrites Ks/Vt
  }

  float inv[4];
#pragma unroll
  for (int j = 0; j < 4; j++) inv[j] = 1.0f / lrun[j];
#pragma unroll
  for (int ni = 0; ni < 4; ni++) {
#pragma unroll
    for (int j = 0; j < 4; j++) {
      int qr = (wid << 4) + ((lane >> 4) << 2) + j;
      int d = (ni << 4) + r4;
      AO[(size_t)(b * SS + q0 + qr) * DD + h * 64 + d] = f2b(o[ni][j] * inv[j]);
    }
  }
}

// ---------------------------------------------------------------------------
extern "C" void kernel_launch(void* const* d_in, const int* in_sizes, int n_in,
                              void* d_out, int out_size, void* d_ws,
                              size_t ws_size, hipStream_t stream) {
  const float* X    = (const float*)d_in[0];
  const int*   vln  = (const int*)d_in[1];
  const float* ln1g = (const float*)d_in[2];
  const float* ln1b = (const float*)d_in[3];
  const float* Wq   = (const float*)d_in[4];
  const float* Wk   = (const float*)d_in[5];
  const float* Wv   = (const float*)d_in[6];
  const float* Wo   = (const float*)d_in[7];
  const float* ln2g = (const float*)d_in[8];
  const float* ln2b = (const float*)d_in[9];
  const float* W1   = (const float*)d_in[10];
  const float* b1   = (const float*)d_in[11];
  const float* W2   = (const float*)d_in[12];
  const float* b2   = (const float*)d_in[13];
  float* out = (float*)d_out;

  unsigned short* ws = (unsigned short*)d_ws;
  unsigned short* h     = ws;                          // 8192x512
  unsigned short* QKVb  = h     + (size_t)MM * DD;     // 8192x1536
  unsigned short* AOb   = QKVb  + (size_t)MM * LDQKV;  // 8192x512
  unsigned short* mid   = AOb   + (size_t)MM * DD;     // 8192x2048
  unsigned short* Wqkvt = mid   + (size_t)MM * FF;     // 1536x512
  unsigned short* Wot   = Wqkvt + (size_t)3 * DD * DD; // 512x512
  unsigned short* W1t   = Wot   + (size_t)DD * DD;     // 2048x512
  unsigned short* W2t   = W1t   + (size_t)FF * DD;     // 512x2048

  dim3 blk(256);

  // weight prep: transpose + convert to bf16 [N][K]
  tconv<<<dim3(16, 16), blk, 0, stream>>>(Wq, Wqkvt, DD, DD);
  tconv<<<dim3(16, 16), blk, 0, stream>>>(Wk, Wqkvt + (size_t)DD * DD, DD, DD);
  tconv<<<dim3(16, 16), blk, 0, stream>>>(Wv, Wqkvt + (size_t)2 * DD * DD, DD, DD);
  tconv<<<dim3(16, 16), blk, 0, stream>>>(Wo, Wot, DD, DD);
  tconv<<<dim3(64, 16), blk, 0, stream>>>(W1, W1t, DD, FF);
  tconv<<<dim3(16, 64), blk, 0, stream>>>(W2, W2t, FF, DD);

  // 1. h = bf16(LN1(X))
  ln_bf16<<<dim3(MM / 4), blk, 0, stream>>>(X, ln1g, ln1b, h);
  // 2. QKV = h @ [Wq|Wk|Wv]  (bf16 out)  [128x128 tile, 768 blocks]
  gemm_t<128, 128, 0><<<dim3(LDQKV / 128, MM / 128), blk, 0, stream>>>(
      h, Wqkvt, nullptr, nullptr, nullptr, QKVb, MM, LDQKV, DD);
  // 3. attention
  attn_mfma<<<dim3(SS / 64, NH, BB), blk, 0, stream>>>(QKVb, vln, AOb);
  // 4. out = X + AO @ Wo   (fp32)  [128x64 tile, 512 blocks]
  gemm_t<128, 64, 0><<<dim3(DD / 64, MM / 128), blk, 0, stream>>>(
      AOb, Wot, nullptr, X, out, nullptr, MM, DD, DD);
  // 5. h2 = bf16(LN2(out))  (overlays h)
  ln_bf16<<<dim3(MM / 4), blk, 0, stream>>>(out, ln2g, ln2b, h);
  // 6. mid = bf16(gelu(h2 @ W1 + b1))  [128x128 tile, 1024 blocks]
  gemm_t<128, 128, 1><<<dim3(FF / 128, MM / 128), blk, 0, stream>>>(
      h, W1t, b1, nullptr, nullptr, mid, MM, FF, DD);
  // 7. out = out + mid @ W2 + b2  (fp32, in-place residual) [128x64, 512 blk]
  gemm_t<128, 64, 0><<<dim3(DD / 64, MM / 128), blk, 0, stream>>>(
      mid, W2t, b2, out, out, nullptr, MM, DD, FF);
}

// Round 4
// 211.935 us; speedup vs baseline: 4.9196x; 1.0091x over previous
//
#include <hip/hip_runtime.h>
#include <math.h>

#define BB 8
#define SS 1024
#define DD 512
#define FF 2048
#define NH 8
#define MM (BB * SS)     // 8192 rows
#define LDQKV 1536       // QKV buffer row stride (Q|K|V concatenated)

using bf8 = __attribute__((ext_vector_type(8))) short;   // 8 x bf16 (4 VGPR)
using f4  = __attribute__((ext_vector_type(4))) float;   // MFMA accumulator

#define AS1 __attribute__((address_space(1)))
#define AS3 __attribute__((address_space(3)))

__device__ __forceinline__ void gload16(const void* g, void* l) {
  // async global->LDS, 16B per lane; LDS dest = wave-uniform base + lane*16
  __builtin_amdgcn_global_load_lds((AS1 const void*)g, (AS3 void*)l, 16, 0, 0);
}

template <int N> __device__ __forceinline__ void wait_vm() {
  if constexpr (N == 0)      asm volatile("s_waitcnt vmcnt(0)" ::: "memory");
  else if constexpr (N == 4) asm volatile("s_waitcnt vmcnt(4)" ::: "memory");
  else if constexpr (N == 6) asm volatile("s_waitcnt vmcnt(6)" ::: "memory");
  else if constexpr (N == 8) asm volatile("s_waitcnt vmcnt(8)" ::: "memory");
  else                       asm volatile("s_waitcnt vmcnt(12)" ::: "memory");
  __builtin_amdgcn_sched_barrier(0);
}

__device__ __forceinline__ void bar() {
  __builtin_amdgcn_sched_barrier(0);
  __builtin_amdgcn_s_barrier();
  __builtin_amdgcn_sched_barrier(0);
}

__device__ __forceinline__ unsigned short f2b(float f) {  // fp32 -> bf16 RNE
  union { float f; unsigned u; } v; v.f = f;
  unsigned r = v.u + 0x7fffu + ((v.u >> 16) & 1u);
  return (unsigned short)(r >> 16);
}

// ---------------------------------------------------------------------------
// LayerNorm fp32 -> bf16. One wave per row of 512. grid = MM/4, block = 256.
// ---------------------------------------------------------------------------
__global__ __launch_bounds__(256) void ln_bf16(const float* __restrict__ x,
                                               const float* __restrict__ g,
                                               const float* __restrict__ bta,
                                               unsigned short* __restrict__ out) {
  int wave = threadIdx.x >> 6, lane = threadIdx.x & 63;
  int row = (blockIdx.x << 2) + wave;
  const float* xr = x + (size_t)row * DD;
  int base = lane << 3;
  float4 v0 = *(const float4*)(xr + base);
  float4 v1 = *(const float4*)(xr + base + 4);
  float s  = v0.x + v0.y + v0.z + v0.w + v1.x + v1.y + v1.z + v1.w;
  float sq = v0.x*v0.x + v0.y*v0.y + v0.z*v0.z + v0.w*v0.w
           + v1.x*v1.x + v1.y*v1.y + v1.z*v1.z + v1.w*v1.w;
  for (int m = 32; m; m >>= 1) { s += __shfl_xor(s, m); sq += __shfl_xor(sq, m); }
  float mu  = s * (1.0f / DD);
  float var = sq * (1.0f / DD) - mu * mu;
  float rs  = rsqrtf(var + 1e-5f);
  float xv[8], go[8], bo[8];
  *(float4*)(xv) = v0; *(float4*)(xv + 4) = v1;
  *(float4*)(go)     = *(const float4*)(g + base);
  *(float4*)(go + 4) = *(const float4*)(g + base + 4);
  *(float4*)(bo)     = *(const float4*)(bta + base);
  *(float4*)(bo + 4) = *(const float4*)(bta + base + 4);
  union { unsigned short u[8]; uint4 v; } ov;
#pragma unroll
  for (int i = 0; i < 8; i++) ov.u[i] = f2b((xv[i] - mu) * rs * go[i] + bo[i]);
  *(uint4*)(out + (size_t)row * DD + base) = ov.v;
}

// ---------------------------------------------------------------------------
// Transpose + fp32->bf16: in [K][N] fp32 -> out [N][K] bf16. grid(N/32, K/32).
// ---------------------------------------------------------------------------
__global__ __launch_bounds__(256) void tconv(const float* __restrict__ in,
                                             unsigned short* __restrict__ outp,
                                             int K, int N) {
  __shared__ float tile[32][33];
  int n0 = blockIdx.x << 5, k0 = blockIdx.y << 5;
  int c = threadIdx.x & 31, r = threadIdx.x >> 5;  // r = 0..7
#pragma unroll
  for (int i = 0; i < 4; i++)
    tile[r + 8 * i][c] = in[(size_t)(k0 + r + 8 * i) * N + n0 + c];
  __syncthreads();
#pragma unroll
  for (int i = 0; i < 4; i++)
    outp[(size_t)(n0 + r + 8 * i) * K + k0 + c] = f2b(tile[c][r + 8 * i]);
}

// ---------------------------------------------------------------------------
// bf16 MFMA GEMM, templated tile: C[M,N] = epi(A[M,K] @ Bt[N,K]^T)
// BK=64, double-buffered LDS, depth-2 prefetch with COUNTED vmcnt (T4):
// raw s_barrier, per-iter wait vmcnt(L) keeps next tile's L loads in flight.
// 256 threads = 4 waves (2x2), wave = (BM/2)x(BN/2).
// LDS rows are 128B = 8 x 16B slots, slot-swizzle slot^=(row&7); applied on
// the global SOURCE of global_load_lds and on the ds_read address (rule #21).
// epi: +bias (fp32), ACT(1=gelu exact), +res (fp32), out fp32 or bf16.
// ---------------------------------------------------------------------------
template <int BM, int BN, int ACT>
__global__ __launch_bounds__(256) void gemm_t(
    const unsigned short* __restrict__ A,   // [M][K] bf16
    const unsigned short* __restrict__ Bt,  // [N][K] bf16
    const float* __restrict__ bias,         // [N] or null
    const float* __restrict__ res,          // [M][N] fp32 or null
    float* __restrict__ Cf,                 // fp32 out (or null)
    unsigned short* __restrict__ Cb,        // bf16 out (or null)
    int M, int N, int K) {
  constexpr int WM = BM / 2, WN = BN / 2;
  constexpr int FM = WM / 16, FN = WN / 16;
  constexpr int ACH = BM / 32, BCH = BN / 32;  // 1KB chunks per wave
  constexpr int L = ACH + BCH;                 // per-wave loads per K-step
  __shared__ unsigned short As[2][BM * 64];
  __shared__ unsigned short Bs[2][BN * 64];
  int tid = threadIdx.x, wid = tid >> 6, lane = tid & 63;
  int m0 = blockIdx.y * BM, n0 = blockIdx.x * BN;
  int wm = (wid >> 1) * WM, wn = (wid & 1) * WN;
  int r4 = lane & 15, ksl = lane >> 4;
  int srow = lane >> 3, gs = (lane & 7) ^ srow;  // inverse-swizzled 16B slot

  const unsigned short* aBase =
      A + (size_t)(m0 + wid * (ACH * 8) + srow) * K + gs * 8;
  const unsigned short* bBase =
      Bt + (size_t)(n0 + wid * (BCH * 8) + srow) * K + gs * 8;

  f4 acc[FM][FN];
#pragma unroll
  for (int i = 0; i < FM; i++)
#pragma unroll
    for (int j = 0; j < FN; j++) acc[i][j] = (f4){0.f, 0.f, 0.f, 0.f};

  auto STAGE = [&](int buf, int t) {
    int k0 = t << 6;
#pragma unroll
    for (int i = 0; i < ACH; i++)
      gload16(aBase + (size_t)i * 8 * K + k0, &As[buf][(wid * ACH + i) * 512]);
#pragma unroll
    for (int i = 0; i < BCH; i++)
      gload16(bBase + (size_t)i * 8 * K + k0, &Bs[buf][(wid * BCH + i) * 512]);
  };

  auto COMPUTE = [&](int buf) {
#pragma unroll
    for (int k2 = 0; k2 < 2; k2++) {
      bf8 af[FM], bfr[FN];
#pragma unroll
      for (int mi = 0; mi < FM; mi++) {
        int r = wm + mi * 16 + r4;
        af[mi] = *(const bf8*)((const char*)&As[buf][0] + r * 128 +
                               (((k2 * 4 + ksl) ^ (r & 7)) << 4));
      }
#pragma unroll
      for (int ni = 0; ni < FN; ni++) {
        int r = wn + ni * 16 + r4;
        bfr[ni] = *(const bf8*)((const char*)&Bs[buf][0] + r * 128 +
                                (((k2 * 4 + ksl) ^ (r & 7)) << 4));
      }
#pragma unroll
      for (int mi = 0; mi < FM; mi++)
#pragma unroll
        for (int ni = 0; ni < FN; ni++)
          acc[mi][ni] = __builtin_amdgcn_mfma_f32_16x16x32_bf16(
              af[mi], bfr[ni], acc[mi][ni], 0, 0, 0);
    }
  };

  int nt = K >> 6;  // >= 8 for all our shapes
  STAGE(0, 0);
  STAGE(1, 1);
  for (int t = 0; t < nt; t++) {
    if (t + 1 < nt) wait_vm<L>();   // tile t landed; tile t+1 stays in flight
    else            wait_vm<0>();   // last tile: drain
    bar();
    COMPUTE(t & 1);
    bar();                          // all waves done reading buf[t&1]
    if (t + 2 < nt) STAGE(t & 1, t + 2);
  }

  int rq = (lane >> 4) << 2;
#pragma unroll
  for (int ni = 0; ni < FN; ni++) {
    int col = n0 + wn + ni * 16 + r4;
    float bv = bias ? bias[col] : 0.0f;
#pragma unroll
    for (int mi = 0; mi < FM; mi++) {
#pragma unroll
      for (int j = 0; j < 4; j++) {
        int row = m0 + wm + mi * 16 + rq + j;
        float v = acc[mi][ni][j] + bv;
        if (ACT) v = 0.5f * v * (1.0f + erff(v * 0.70710678118654752f));
        if (res) v += res[(size_t)row * N + col];
        if (Cf) Cf[(size_t)row * N + col] = v;
        else    Cb[(size_t)row * N + col] = f2b(v);
      }
    }
  }
}

// ---------------------------------------------------------------------------
// Flash attention, bf16 MFMA. grid (S/64, NH, B), block 256 (4 waves).
// Wave w owns q-rows w*16..w*16+15 of the 64-row Q tile.
// All LDS tiles are 64 rows x 64 bf16 (128B rows, 8 slots), slot^=(row&7).
// ---------------------------------------------------------------------------
__global__ __launch_bounds__(256) void attn_mfma(
    const unsigned short* __restrict__ QKV,  // [B*S][1536]
    const int* __restrict__ vlen,
    unsigned short* __restrict__ AO) {       // [B*S][512]
  __shared__ unsigned short Qs[64 * 64];
  __shared__ unsigned short Ks[64 * 64];
  __shared__ unsigned short Vt[64 * 64];     // transposed: [d][k]
  __shared__ unsigned short Ps[64 * 64];     // [q][k]
  int b = blockIdx.z, h = blockIdx.y, q0 = blockIdx.x << 6;
  int tid = threadIdx.x, wid = tid >> 6, lane = tid & 63;
  int vl = vlen[b];
  int r4 = lane & 15, ksl = lane >> 4;

  // ---- stage Q (2 chunks of 1KB per wave; chunk = 8 rows of 128B)
  int srow = lane >> 3;                 // 0..7
  int gs = (lane & 7) ^ srow;           // inverse-swizzled 16B slot
  {
    const unsigned short* qsrc =
        QKV + (size_t)(b * SS + q0 + wid * 16 + srow) * LDQKV + h * 64 + gs * 8;
    gload16(qsrc, Qs + wid * 1024);
    gload16(qsrc + (size_t)8 * LDQKV, Qs + wid * 1024 + 512);
  }
  const unsigned short* kbase =
      QKV + (size_t)(b * SS + wid * 16 + srow) * LDQKV + DD + h * 64 + gs * 8;
  int vp = tid & 31, vdg = (tid >> 5) << 3;
  const unsigned short* vbase =
      QKV + (size_t)(b * SS + 2 * vp) * LDQKV + 2 * DD + h * 64 + vdg;

  f4 o[4];
#pragma unroll
  for (int i = 0; i < 4; i++) o[i] = (f4){0.f, 0.f, 0.f, 0.f};
  float mrun[4], lrun[4];
#pragma unroll
  for (int j = 0; j < 4; j++) { mrun[j] = -3e38f; lrun[j] = 0.0f; }

  int ntiles = (vl + 63) >> 6;
  if (ntiles > 16) ntiles = 16;

  for (int t = 0; t < ntiles; t++) {
    int kg0 = t << 6;
    // stage K via global_load_lds
    const unsigned short* ks = kbase + (size_t)kg0 * LDQKV;
    gload16(ks, Ks + wid * 1024);
    gload16(ks + (size_t)8 * LDQKV, Ks + wid * 1024 + 512);
    // stage V transposed: pack key-pairs into u32, swizzled ds_write_b32
    {
      const unsigned short* v0 = vbase + (size_t)kg0 * LDQKV;
      const unsigned short* v1 = v0 + LDQKV;
      unsigned short va[8], vb[8];
      *(uint4*)va = *(const uint4*)v0;
      *(uint4*)vb = *(const uint4*)v1;
#pragma unroll
      for (int i = 0; i < 8; i++) {
        int d = vdg + i;
        unsigned val = (unsigned)va[i] | ((unsigned)vb[i] << 16);
        int byte = (d << 7) + (((vp >> 2) ^ (d & 7)) << 4) + ((vp & 3) << 2);
        *(unsigned*)((char*)Vt + byte) = val;
      }
    }
    __syncthreads();

    // ---- S = Q @ K^T  (rows: this wave's 16 q; cols: 64 keys)
    f4 s[4];
#pragma unroll
    for (int i = 0; i < 4; i++) s[i] = (f4){0.f, 0.f, 0.f, 0.f};
#pragma unroll
    for (int k2 = 0; k2 < 2; k2++) {
      int slot = (k2 << 2) + ksl;
      int qr = (wid << 4) + r4;
      bf8 aq = *(const bf8*)((const char*)Qs + (qr << 7) + ((slot ^ (qr & 7)) << 4));
#pragma unroll
      for (int ni = 0; ni < 4; ni++) {
        int kr = (ni << 4) + r4;
        bf8 bk = *(const bf8*)((const char*)Ks + (kr << 7) + ((slot ^ (kr & 7)) << 4));
        s[ni] = __builtin_amdgcn_mfma_f32_16x16x32_bf16(aq, bk, s[ni], 0, 0, 0);
      }
    }

    // ---- online softmax (rows in-register; 16-lane shfl reduce)
#pragma unroll
    for (int j = 0; j < 4; j++) {
      int qr = (wid << 4) + ((lane >> 4) << 2) + j;
      float sv[4], mx = -3e38f;
#pragma unroll
      for (int ni = 0; ni < 4; ni++) {
        float v = s[ni][j] * 0.125f;                       // 1/sqrt(64)
        if (kg0 + (ni << 4) + r4 >= vl) v = -1e6f;         // masked_softmax
        sv[ni] = v;
        mx = fmaxf(mx, v);
      }
#pragma unroll
      for (int m2 = 1; m2 < 16; m2 <<= 1) mx = fmaxf(mx, __shfl_xor(mx, m2));
      float mnew = fmaxf(mrun[j], mx);
      float al = __expf(mrun[j] - mnew);
      float ls = 0.0f;
      unsigned short pb[4];
#pragma unroll
      for (int ni = 0; ni < 4; ni++) {
        float p = __expf(sv[ni] - mnew);
        ls += p;
        pb[ni] = f2b(p);
      }
#pragma unroll
      for (int m2 = 1; m2 < 16; m2 <<= 1) ls += __shfl_xor(ls, m2);
      lrun[j] = lrun[j] * al + ls;
      mrun[j] = mnew;
#pragma unroll
      for (int ni = 0; ni < 4; ni++) {
        int kc = (ni << 4) + r4;
        int byte = (qr << 7) + (((kc >> 3) ^ (qr & 7)) << 4) + ((kc & 7) << 1);
        *(unsigned short*)((char*)Ps + byte) = pb[ni];
        o[ni][j] *= al;
      }
    }

    // ---- O += P @ V   (A = P rows of this wave; B cols = d via Vt)
#pragma unroll
    for (int k2 = 0; k2 < 2; k2++) {
      int slot = (k2 << 2) + ksl;
      int qr = (wid << 4) + r4;
      bf8 ap = *(const bf8*)((const char*)Ps + (qr << 7) + ((slot ^ (qr & 7)) << 4));
#pragma unroll
      for (int ni = 0; ni < 4; ni++) {
        int dr = (ni << 4) + r4;
        bf8 bv = *(const bf8*)((const char*)Vt + (dr << 7) + ((slot ^ (dr & 7)) << 4));
        o[ni] = __builtin_amdgcn_mfma_f32_16x16x32_bf16(ap, bv, o[ni], 0, 0, 0);
      }
    }
    __syncthreads();  // before next tile overwrites Ks/Vt
  }

  float inv[4];
#pragma unroll
  for (int j = 0; j < 4; j++) inv[j] = 1.0f / lrun[j];
#pragma unroll
  for (int ni = 0; ni < 4; ni++) {
#pragma unroll
    for (int j = 0; j < 4; j++) {
      int qr = (wid << 4) + ((lane >> 4) << 2) + j;
      int d = (ni << 4) + r4;
      AO[(size_t)(b * SS + q0 + qr) * DD + h * 64 + d] = f2b(o[ni][j] * inv[j]);
    }
  }
}

// ---------------------------------------------------------------------------
extern "C" void kernel_launch(void* const* d_in, const int* in_sizes, int n_in,
                              void* d_out, int out_size, void* d_ws,
                              size_t ws_size, hipStream_t stream) {
  const float* X    = (const float*)d_in[0];
  const int*   vln  = (const int*)d_in[1];
  const float* ln1g = (const float*)d_in[2];
  const float* ln1b = (const float*)d_in[3];
  const float* Wq   = (const float*)d_in[4];
  const float* Wk   = (const float*)d_in[5];
  const float* Wv   = (const float*)d_in[6];
  const float* Wo   = (const float*)d_in[7];
  const float* ln2g = (const float*)d_in[8];
  const float* ln2b = (const float*)d_in[9];
  const float* W1   = (const float*)d_in[10];
  const float* b1   = (const float*)d_in[11];
  const float* W2   = (const float*)d_in[12];
  const float* b2   = (const float*)d_in[13];
  float* out = (float*)d_out;

  unsigned short* ws = (unsigned short*)d_ws;
  unsigned short* h     = ws;                          // 8192x512
  unsigned short* QKVb  = h     + (size_t)MM * DD;     // 8192x1536
  unsigned short* AOb   = QKVb  + (size_t)MM * LDQKV;  // 8192x512
  unsigned short* mid   = AOb   + (size_t)MM * DD;     // 8192x2048
  unsigned short* Wqkvt = mid   + (size_t)MM * FF;     // 1536x512
  unsigned short* Wot   = Wqkvt + (size_t)3 * DD * DD; // 512x512
  unsigned short* W1t   = Wot   + (size_t)DD * DD;     // 2048x512
  unsigned short* W2t   = W1t   + (size_t)FF * DD;     // 512x2048

  dim3 blk(256);

  // weight prep: transpose + convert to bf16 [N][K]
  tconv<<<dim3(16, 16), blk, 0, stream>>>(Wq, Wqkvt, DD, DD);
  tconv<<<dim3(16, 16), blk, 0, stream>>>(Wk, Wqkvt + (size_t)DD * DD, DD, DD);
  tconv<<<dim3(16, 16), blk, 0, stream>>>(Wv, Wqkvt + (size_t)2 * DD * DD, DD, DD);
  tconv<<<dim3(16, 16), blk, 0, stream>>>(Wo, Wot, DD, DD);
  tconv<<<dim3(64, 16), blk, 0, stream>>>(W1, W1t, DD, FF);
  tconv<<<dim3(16, 64), blk, 0, stream>>>(W2, W2t, FF, DD);

  // 1. h = bf16(LN1(X))
  ln_bf16<<<dim3(MM / 4), blk, 0, stream>>>(X, ln1g, ln1b, h);
  // 2. QKV = h @ [Wq|Wk|Wv]  (bf16 out)  [128x128 tile, 768 blocks]
  gemm_t<128, 128, 0><<<dim3(LDQKV / 128, MM / 128), blk, 0, stream>>>(
      h, Wqkvt, nullptr, nullptr, nullptr, QKVb, MM, LDQKV, DD);
  // 3. attention
  attn_mfma<<<dim3(SS / 64, NH, BB), blk, 0, stream>>>(QKVb, vln, AOb);
  // 4. out = X + AO @ Wo   (fp32)  [128x64 tile, 512 blocks]
  gemm_t<128, 64, 0><<<dim3(DD / 64, MM / 128), blk, 0, stream>>>(
      AOb, Wot, nullptr, X, out, nullptr, MM, DD, DD);
  // 5. h2 = bf16(LN2(out))  (overlays h)
  ln_bf16<<<dim3(MM / 4), blk, 0, stream>>>(out, ln2g, ln2b, h);
  // 6. mid = bf16(gelu(h2 @ W1 + b1))  [128x128 tile, 1024 blocks]
  gemm_t<128, 128, 1><<<dim3(FF / 128, MM / 128), blk, 0, stream>>>(
      h, W1t, b1, nullptr, nullptr, mid, MM, FF, DD);
  // 7. out = out + mid @ W2 + b2  (fp32, in-place residual) [128x64, 512 blk]
  gemm_t<128, 64, 0><<<dim3(DD / 64, MM / 128), blk, 0, stream>>>(
      mid, W2t, b2, out, out, nullptr, MM, DD, FF);
}

// Round 5
// 179.368 us; speedup vs baseline: 5.8128x; 1.1816x over previous
//
#include <hip/hip_runtime.h>
#include <math.h>

#define BB 8
#define SS 1024
#define DD 512
#define FF 2048
#define NH 8
#define MM (BB * SS)     // 8192 rows
#define LDQKV 1536       // QKV buffer row stride (Q|K|V concatenated)

using bf8 = __attribute__((ext_vector_type(8))) short;   // 8 x bf16 (4 VGPR)
using f4  = __attribute__((ext_vector_type(4))) float;   // MFMA accumulator

#define AS1 __attribute__((address_space(1)))
#define AS3 __attribute__((address_space(3)))

__device__ __forceinline__ void gload16(const void* g, void* l) {
  // async global->LDS, 16B per lane; LDS dest = wave-uniform base + lane*16
  __builtin_amdgcn_global_load_lds((AS1 const void*)g, (AS3 void*)l, 16, 0, 0);
}

template <int N> __device__ __forceinline__ void wait_vm() {
  if constexpr (N == 0)      asm volatile("s_waitcnt vmcnt(0)" ::: "memory");
  else if constexpr (N == 3) asm volatile("s_waitcnt vmcnt(3)" ::: "memory");
  else if constexpr (N == 4) asm volatile("s_waitcnt vmcnt(4)" ::: "memory");
  else if constexpr (N == 6) asm volatile("s_waitcnt vmcnt(6)" ::: "memory");
  else                       asm volatile("s_waitcnt vmcnt(8)" ::: "memory");
  __builtin_amdgcn_sched_barrier(0);
}

__device__ __forceinline__ void bar() {
  __builtin_amdgcn_sched_barrier(0);
  __builtin_amdgcn_s_barrier();
  __builtin_amdgcn_sched_barrier(0);
}

__device__ __forceinline__ unsigned short f2b(float f) {  // fp32 -> bf16 RNE
  union { float f; unsigned u; } v; v.f = f;
  unsigned r = v.u + 0x7fffu + ((v.u >> 16) & 1u);
  return (unsigned short)(r >> 16);
}

// gelu exact via A&S 7.1.26 erf approx (|eps| <= 1.5e-7)
__device__ __forceinline__ float gelu_f(float x) {
  float ax = fabsf(x) * 0.70710678118654752f;
  float t = 1.0f / (1.0f + 0.3275911f * ax);
  float poly = t * (0.254829592f +
               t * (-0.284496736f +
               t * (1.421413741f +
               t * (-1.453152027f + t * 1.061405429f))));
  float erfv = 1.0f - poly * __expf(-ax * ax);
  erfv = copysignf(erfv, x);
  return 0.5f * x * (1.0f + erfv);
}

// ---------------------------------------------------------------------------
// LayerNorm fp32 -> bf16. One wave per row of 512. grid = MM/4, block = 256.
// ---------------------------------------------------------------------------
__global__ __launch_bounds__(256) void ln_bf16(const float* __restrict__ x,
                                               const float* __restrict__ g,
                                               const float* __restrict__ bta,
                                               unsigned short* __restrict__ out) {
  int wave = threadIdx.x >> 6, lane = threadIdx.x & 63;
  int row = (blockIdx.x << 2) + wave;
  const float* xr = x + (size_t)row * DD;
  int base = lane << 3;
  float4 v0 = *(const float4*)(xr + base);
  float4 v1 = *(const float4*)(xr + base + 4);
  float s  = v0.x + v0.y + v0.z + v0.w + v1.x + v1.y + v1.z + v1.w;
  float sq = v0.x*v0.x + v0.y*v0.y + v0.z*v0.z + v0.w*v0.w
           + v1.x*v1.x + v1.y*v1.y + v1.z*v1.z + v1.w*v1.w;
  for (int m = 32; m; m >>= 1) { s += __shfl_xor(s, m); sq += __shfl_xor(sq, m); }
  float mu  = s * (1.0f / DD);
  float var = sq * (1.0f / DD) - mu * mu;
  float rs  = rsqrtf(var + 1e-5f);
  float xv[8], go[8], bo[8];
  *(float4*)(xv) = v0; *(float4*)(xv + 4) = v1;
  *(float4*)(go)     = *(const float4*)(g + base);
  *(float4*)(go + 4) = *(const float4*)(g + base + 4);
  *(float4*)(bo)     = *(const float4*)(bta + base);
  *(float4*)(bo + 4) = *(const float4*)(bta + base + 4);
  union { unsigned short u[8]; uint4 v; } ov;
#pragma unroll
  for (int i = 0; i < 8; i++) ov.u[i] = f2b((xv[i] - mu) * rs * go[i] + bo[i]);
  *(uint4*)(out + (size_t)row * DD + base) = ov.v;
}

// ---------------------------------------------------------------------------
// Transpose + fp32->bf16: in [K][N] fp32 -> out [N][K] bf16. grid(N/32, K/32).
// ---------------------------------------------------------------------------
__global__ __launch_bounds__(256) void tconv(const float* __restrict__ in,
                                             unsigned short* __restrict__ outp,
                                             int K, int N) {
  __shared__ float tile[32][33];
  int n0 = blockIdx.x << 5, k0 = blockIdx.y << 5;
  int c = threadIdx.x & 31, r = threadIdx.x >> 5;  // r = 0..7
#pragma unroll
  for (int i = 0; i < 4; i++)
    tile[r + 8 * i][c] = in[(size_t)(k0 + r + 8 * i) * N + n0 + c];
  __syncthreads();
#pragma unroll
  for (int i = 0; i < 4; i++)
    outp[(size_t)(n0 + r + 8 * i) * K + k0 + c] = f2b(tile[c][r + 8 * i]);
}

// fused 4x 512x512 transpose+convert; blockIdx.z selects the weight
__global__ __launch_bounds__(256) void tconv4(
    const float* __restrict__ s0, const float* __restrict__ s1,
    const float* __restrict__ s2, const float* __restrict__ s3,
    unsigned short* __restrict__ d0, unsigned short* __restrict__ d1,
    unsigned short* __restrict__ d2, unsigned short* __restrict__ d3) {
  __shared__ float tile[32][33];
  const float* in; unsigned short* outp;
  switch (blockIdx.z) {
    case 0: in = s0; outp = d0; break;
    case 1: in = s1; outp = d1; break;
    case 2: in = s2; outp = d2; break;
    default: in = s3; outp = d3; break;
  }
  int n0 = blockIdx.x << 5, k0 = blockIdx.y << 5;
  int c = threadIdx.x & 31, r = threadIdx.x >> 5;
#pragma unroll
  for (int i = 0; i < 4; i++)
    tile[r + 8 * i][c] = in[(size_t)(k0 + r + 8 * i) * DD + n0 + c];
  __syncthreads();
#pragma unroll
  for (int i = 0; i < 4; i++)
    outp[(size_t)(n0 + r + 8 * i) * DD + k0 + c] = f2b(tile[c][r + 8 * i]);
}

// ---------------------------------------------------------------------------
// bf16 MFMA GEMM: C[M,N] = epi(A[M,K] @ Bt[N,K]^T)
// BK=32, double-buffered LDS (32 KB at 128x128 -> 4 blocks/CU), counted-vmcnt
// depth-2 prefetch. 256 threads = 4 waves (2x2). 1D grid + XCD swizzle.
// LDS rows are 64B = 4 x 16B slots; read slot = ksl ^ ((row>>1)&3), staging
// global source inverse-permuted to match (rule #21). <=2-way conflicts.
// MFMA operands SWAPPED (mfma(B,A)) so each lane's 4 acc elems are 4
// consecutive COLUMNS -> vectorized epilogue stores (ushort4 / float4).
// ---------------------------------------------------------------------------
template <int BM, int BN, int ACT>
__global__ __launch_bounds__(256, 4) void gemm_t(
    const unsigned short* __restrict__ A,   // [M][K] bf16
    const unsigned short* __restrict__ Bt,  // [N][K] bf16
    const float* __restrict__ bias,         // [N] or null
    const float* __restrict__ res,          // [M][N] fp32 or null
    float* __restrict__ Cf,                 // fp32 out (or null)
    unsigned short* __restrict__ Cb,        // bf16 out (or null)
    int M, int N, int K, int gx) {
  constexpr int WM = BM / 2, WN = BN / 2;
  constexpr int FM = WM / 16, FN = WN / 16;
  constexpr int ACH = BM / 64, BCH = BN / 64;  // 1KB (16-row) chunks per wave
  constexpr int L = ACH + BCH;                 // per-wave loads per K-step
  __shared__ unsigned short As[2][BM * 32];
  __shared__ unsigned short Bs[2][BN * 32];
  int tid = threadIdx.x, wid = tid >> 6, lane = tid & 63;

  // XCD-bijective swizzle (grid % 8 == 0): chunk of nwg/8 blocks per XCD,
  // consecutive blocks share the A m-panel -> L2 locality.
  int bid = blockIdx.x;
  int cpx = (int)gridDim.x >> 3;
  int swz = (bid & 7) * cpx + (bid >> 3);
  int m0 = (swz / gx) * BM, n0 = (swz % gx) * BN;

  int wm = (wid >> 1) * WM, wn = (wid & 1) * WN;
  int r4 = lane & 15, ksl = lane >> 4;
  int srow = lane >> 2;                       // row within 16-row chunk
  int gs = (lane & 3) ^ ((lane >> 3) & 3);    // inverse-swizzled 16B slot

  const unsigned short* aBase =
      A + (size_t)(m0 + wid * (ACH * 16) + srow) * K + gs * 8;
  const unsigned short* bBase =
      Bt + (size_t)(n0 + wid * (BCH * 16) + srow) * K + gs * 8;

  f4 acc[FN][FM];
#pragma unroll
  for (int i = 0; i < FN; i++)
#pragma unroll
    for (int j = 0; j < FM; j++) acc[i][j] = (f4){0.f, 0.f, 0.f, 0.f};

  auto STAGE = [&](int buf, int t) {
    int k0 = t << 5;
#pragma unroll
    for (int i = 0; i < ACH; i++)
      gload16(aBase + (size_t)i * 16 * K + k0, &As[buf][(wid * ACH + i) * 512]);
#pragma unroll
    for (int i = 0; i < BCH; i++)
      gload16(bBase + (size_t)i * 16 * K + k0, &Bs[buf][(wid * BCH + i) * 512]);
  };

  auto COMPUTE = [&](int buf) {
    bf8 af[FM], bfr[FN];
#pragma unroll
    for (int mi = 0; mi < FM; mi++) {
      int r = wm + mi * 16 + r4;
      af[mi] = *(const bf8*)((const char*)&As[buf][0] + r * 64 +
                             ((ksl ^ ((r >> 1) & 3)) << 4));
    }
#pragma unroll
    for (int ni = 0; ni < FN; ni++) {
      int r = wn + ni * 16 + r4;
      bfr[ni] = *(const bf8*)((const char*)&Bs[buf][0] + r * 64 +
                              ((ksl ^ ((r >> 1) & 3)) << 4));
    }
#pragma unroll
    for (int ni = 0; ni < FN; ni++)
#pragma unroll
      for (int mi = 0; mi < FM; mi++)
        acc[ni][mi] = __builtin_amdgcn_mfma_f32_16x16x32_bf16(
            bfr[ni], af[mi], acc[ni][mi], 0, 0, 0);
  };

  int nt = K >> 5;  // >= 16 for all our shapes
  STAGE(0, 0);
  STAGE(1, 1);
  for (int t = 0; t < nt; t++) {
    if (t + 1 < nt) wait_vm<L>();   // tile t landed; tile t+1 stays in flight
    else            wait_vm<0>();   // last tile: drain
    bar();
    COMPUTE(t & 1);
    bar();                          // all waves done reading buf[t&1]
    if (t + 2 < nt) STAGE(t & 1, t + 2);
  }

  // epilogue: lane holds 4 consecutive cols (rq..rq+3) of row r4 per fragment
  int rq = (lane >> 4) << 2;
#pragma unroll
  for (int ni = 0; ni < FN; ni++) {
    int col = n0 + wn + ni * 16 + rq;
    float bv[4] = {0.f, 0.f, 0.f, 0.f};
    if (bias) *(float4*)bv = *(const float4*)(bias + col);
#pragma unroll
    for (int mi = 0; mi < FM; mi++) {
      int row = m0 + wm + mi * 16 + r4;
      float v[4];
#pragma unroll
      for (int j = 0; j < 4; j++) {
        v[j] = acc[ni][mi][j] + bv[j];
        if (ACT) v[j] = gelu_f(v[j]);
      }
      if (res) {
        float4 rv = *(const float4*)(res + (size_t)row * N + col);
        v[0] += rv.x; v[1] += rv.y; v[2] += rv.z; v[3] += rv.w;
      }
      if (Cf) {
        *(float4*)(Cf + (size_t)row * N + col) = *(float4*)v;
      } else {
        union { unsigned short u[4]; uint2 q; } p;
#pragma unroll
        for (int j = 0; j < 4; j++) p.u[j] = f2b(v[j]);
        *(uint2*)(Cb + (size_t)row * N + col) = p.q;
      }
    }
  }
}

// ---------------------------------------------------------------------------
// Flash attention, bf16 MFMA. grid (S/64, NH, B), block 256 (4 waves).
// Wave w owns q-rows w*16..w*16+15 of the 64-row Q tile.
// All LDS tiles are 64 rows x 64 bf16 (128B rows, 8 slots), slot^=(row&7).
// ---------------------------------------------------------------------------
__global__ __launch_bounds__(256) void attn_mfma(
    const unsigned short* __restrict__ QKV,  // [B*S][1536]
    const int* __restrict__ vlen,
    unsigned short* __restrict__ AO) {       // [B*S][512]
  __shared__ unsigned short Qs[64 * 64];
  __shared__ unsigned short Ks[64 * 64];
  __shared__ unsigned short Vt[64 * 64];     // transposed: [d][k]
  __shared__ unsigned short Ps[64 * 64];     // [q][k]
  int b = blockIdx.z, h = blockIdx.y, q0 = blockIdx.x << 6;
  int tid = threadIdx.x, wid = tid >> 6, lane = tid & 63;
  int vl = vlen[b];
  int r4 = lane & 15, ksl = lane >> 4;

  // ---- stage Q (2 chunks of 1KB per wave; chunk = 8 rows of 128B)
  int srow = lane >> 3;                 // 0..7
  int gs = (lane & 7) ^ srow;           // inverse-swizzled 16B slot
  {
    const unsigned short* qsrc =
        QKV + (size_t)(b * SS + q0 + wid * 16 + srow) * LDQKV + h * 64 + gs * 8;
    gload16(qsrc, Qs + wid * 1024);
    gload16(qsrc + (size_t)8 * LDQKV, Qs + wid * 1024 + 512);
  }
  const unsigned short* kbase =
      QKV + (size_t)(b * SS + wid * 16 + srow) * LDQKV + DD + h * 64 + gs * 8;
  int vp = tid & 31, vdg = (tid >> 5) << 3;
  const unsigned short* vbase =
      QKV + (size_t)(b * SS + 2 * vp) * LDQKV + 2 * DD + h * 64 + vdg;

  f4 o[4];
#pragma unroll
  for (int i = 0; i < 4; i++) o[i] = (f4){0.f, 0.f, 0.f, 0.f};
  float mrun[4], lrun[4];
#pragma unroll
  for (int j = 0; j < 4; j++) { mrun[j] = -3e38f; lrun[j] = 0.0f; }

  int ntiles = (vl + 63) >> 6;
  if (ntiles > 16) ntiles = 16;

  for (int t = 0; t < ntiles; t++) {
    int kg0 = t << 6;
    // stage K via global_load_lds
    const unsigned short* ks = kbase + (size_t)kg0 * LDQKV;
    gload16(ks, Ks + wid * 1024);
    gload16(ks + (size_t)8 * LDQKV, Ks + wid * 1024 + 512);
    // stage V transposed: pack key-pairs into u32, swizzled ds_write_b32
    {
      const unsigned short* v0 = vbase + (size_t)kg0 * LDQKV;
      const unsigned short* v1 = v0 + LDQKV;
      unsigned short va[8], vb[8];
      *(uint4*)va = *(const uint4*)v0;
      *(uint4*)vb = *(const uint4*)v1;
#pragma unroll
      for (int i = 0; i < 8; i++) {
        int d = vdg + i;
        unsigned val = (unsigned)va[i] | ((unsigned)vb[i] << 16);
        int byte = (d << 7) + (((vp >> 2) ^ (d & 7)) << 4) + ((vp & 3) << 2);
        *(unsigned*)((char*)Vt + byte) = val;
      }
    }
    __syncthreads();

    // ---- S = Q @ K^T  (rows: this wave's 16 q; cols: 64 keys)
    f4 s[4];
#pragma unroll
    for (int i = 0; i < 4; i++) s[i] = (f4){0.f, 0.f, 0.f, 0.f};
#pragma unroll
    for (int k2 = 0; k2 < 2; k2++) {
      int slot = (k2 << 2) + ksl;
      int qr = (wid << 4) + r4;
      bf8 aq = *(const bf8*)((const char*)Qs + (qr << 7) + ((slot ^ (qr & 7)) << 4));
#pragma unroll
      for (int ni = 0; ni < 4; ni++) {
        int kr = (ni << 4) + r4;
        bf8 bk = *(const bf8*)((const char*)Ks + (kr << 7) + ((slot ^ (kr & 7)) << 4));
        s[ni] = __builtin_amdgcn_mfma_f32_16x16x32_bf16(aq, bk, s[ni], 0, 0, 0);
      }
    }

    // ---- online softmax (rows in-register; 16-lane shfl reduce)
#pragma unroll
    for (int j = 0; j < 4; j++) {
      int qr = (wid << 4) + ((lane >> 4) << 2) + j;
      float sv[4], mx = -3e38f;
#pragma unroll
      for (int ni = 0; ni < 4; ni++) {
        float v = s[ni][j] * 0.125f;                       // 1/sqrt(64)
        if (kg0 + (ni << 4) + r4 >= vl) v = -1e6f;         // masked_softmax
        sv[ni] = v;
        mx = fmaxf(mx, v);
      }
#pragma unroll
      for (int m2 = 1; m2 < 16; m2 <<= 1) mx = fmaxf(mx, __shfl_xor(mx, m2));
      float mnew = fmaxf(mrun[j], mx);
      float al = __expf(mrun[j] - mnew);
      float ls = 0.0f;
      unsigned short pb[4];
#pragma unroll
      for (int ni = 0; ni < 4; ni++) {
        float p = __expf(sv[ni] - mnew);
        ls += p;
        pb[ni] = f2b(p);
      }
#pragma unroll
      for (int m2 = 1; m2 < 16; m2 <<= 1) ls += __shfl_xor(ls, m2);
      lrun[j] = lrun[j] * al + ls;
      mrun[j] = mnew;
#pragma unroll
      for (int ni = 0; ni < 4; ni++) {
        int kc = (ni << 4) + r4;
        int byte = (qr << 7) + (((kc >> 3) ^ (qr & 7)) << 4) + ((kc & 7) << 1);
        *(unsigned short*)((char*)Ps + byte) = pb[ni];
        o[ni][j] *= al;
      }
    }

    // ---- O += P @ V   (A = P rows of this wave; B cols = d via Vt)
#pragma unroll
    for (int k2 = 0; k2 < 2; k2++) {
      int slot = (k2 << 2) + ksl;
      int qr = (wid << 4) + r4;
      bf8 ap = *(const bf8*)((const char*)Ps + (qr << 7) + ((slot ^ (qr & 7)) << 4));
#pragma unroll
      for (int ni = 0; ni < 4; ni++) {
        int dr = (ni << 4) + r4;
        bf8 bv = *(const bf8*)((const char*)Vt + (dr << 7) + ((slot ^ (dr & 7)) << 4));
        o[ni] = __builtin_amdgcn_mfma_f32_16x16x32_bf16(ap, bv, o[ni], 0, 0, 0);
      }
    }
    __syncthreads();  // before next tile overwrites Ks/Vt
  }

  float inv[4];
#pragma unroll
  for (int j = 0; j < 4; j++) inv[j] = 1.0f / lrun[j];
#pragma unroll
  for (int ni = 0; ni < 4; ni++) {
#pragma unroll
    for (int j = 0; j < 4; j++) {
      int qr = (wid << 4) + ((lane >> 4) << 2) + j;
      int d = (ni << 4) + r4;
      AO[(size_t)(b * SS + q0 + qr) * DD + h * 64 + d] = f2b(o[ni][j] * inv[j]);
    }
  }
}

// ---------------------------------------------------------------------------
extern "C" void kernel_launch(void* const* d_in, const int* in_sizes, int n_in,
                              void* d_out, int out_size, void* d_ws,
                              size_t ws_size, hipStream_t stream) {
  const float* X    = (const float*)d_in[0];
  const int*   vln  = (const int*)d_in[1];
  const float* ln1g = (const float*)d_in[2];
  const float* ln1b = (const float*)d_in[3];
  const float* Wq   = (const float*)d_in[4];
  const float* Wk   = (const float*)d_in[5];
  const float* Wv   = (const float*)d_in[6];
  const float* Wo   = (const float*)d_in[7];
  const float* ln2g = (const float*)d_in[8];
  const float* ln2b = (const float*)d_in[9];
  const float* W1   = (const float*)d_in[10];
  const float* b1   = (const float*)d_in[11];
  const float* W2   = (const float*)d_in[12];
  const float* b2   = (const float*)d_in[13];
  float* out = (float*)d_out;

  unsigned short* ws = (unsigned short*)d_ws;
  unsigned short* h     = ws;                          // 8192x512
  unsigned short* QKVb  = h     + (size_t)MM * DD;     // 8192x1536
  unsigned short* AOb   = QKVb  + (size_t)MM * LDQKV;  // 8192x512
  unsigned short* mid   = AOb   + (size_t)MM * DD;     // 8192x2048
  unsigned short* Wqkvt = mid   + (size_t)MM * FF;     // 1536x512
  unsigned short* Wot   = Wqkvt + (size_t)3 * DD * DD; // 512x512
  unsigned short* W1t   = Wot   + (size_t)DD * DD;     // 2048x512
  unsigned short* W2t   = W1t   + (size_t)FF * DD;     // 512x2048

  dim3 blk(256);

  // weight prep: transpose + convert to bf16 [N][K]
  tconv4<<<dim3(16, 16, 4), blk, 0, stream>>>(
      Wq, Wk, Wv, Wo, Wqkvt, Wqkvt + (size_t)DD * DD,
      Wqkvt + (size_t)2 * DD * DD, Wot);
  tconv<<<dim3(64, 16), blk, 0, stream>>>(W1, W1t, DD, FF);
  tconv<<<dim3(16, 64), blk, 0, stream>>>(W2, W2t, FF, DD);

  // 1. h = bf16(LN1(X))
  ln_bf16<<<dim3(MM / 4), blk, 0, stream>>>(X, ln1g, ln1b, h);
  // 2. QKV = h @ [Wq|Wk|Wv]  (bf16 out)  [768 blocks]
  gemm_t<128, 128, 0><<<dim3((LDQKV / 128) * (MM / 128)), blk, 0, stream>>>(
      h, Wqkvt, nullptr, nullptr, nullptr, QKVb, MM, LDQKV, DD, LDQKV / 128);
  // 3. attention
  attn_mfma<<<dim3(SS / 64, NH, BB), blk, 0, stream>>>(QKVb, vln, AOb);
  // 4. out = X + AO @ Wo   (fp32)  [512 blocks]
  gemm_t<128, 64, 0><<<dim3((DD / 64) * (MM / 128)), blk, 0, stream>>>(
      AOb, Wot, nullptr, X, out, nullptr, MM, DD, DD, DD / 64);
  // 5. h2 = bf16(LN2(out))  (overlays h)
  ln_bf16<<<dim3(MM / 4), blk, 0, stream>>>(out, ln2g, ln2b, h);
  // 6. mid = bf16(gelu(h2 @ W1 + b1))  [1024 blocks]
  gemm_t<128, 128, 1><<<dim3((FF / 128) * (MM / 128)), blk, 0, stream>>>(
      h, W1t, b1, nullptr, nullptr, mid, MM, FF, DD, FF / 128);
  // 7. out = out + mid @ W2 + b2  (fp32, in-place residual)  [512 blocks]
  gemm_t<128, 64, 0><<<dim3((DD / 64) * (MM / 128)), blk, 0, stream>>>(
      mid, W2t, b2, out, out, nullptr, MM, DD, FF, DD / 64);
}